// Round 8
// baseline (541.738 us; speedup 1.0000x reference)
//
#include <hip/hip_runtime.h>
#include <math.h>

typedef unsigned short u16;
typedef signed char i8;
typedef short s8v __attribute__((ext_vector_type(8)));   // 8 bf16 (4 VGPRs)
typedef float f4v __attribute__((ext_vector_type(4)));   // 4 fp32 acc
typedef int   i4v __attribute__((ext_vector_type(4)));   // 4 i32 (16 i8 / i32 acc)

constexpr int Bv = 8, Tv = 2048, Cv = 768, Hv = 3072;
constexpr int BT = Bv * Tv;       // 16384 tokens
constexpr int BC = Bv * Cv;       // 6144 channels
constexpr int Lc = 128;           // WKV chunk length
constexpr int NCHK = Tv / Lc;     // 16 chunks
constexpr int KVS = 2304;         // fused k|v|sr row stride

__device__ __forceinline__ float b2f(u16 x) { return __uint_as_float(((unsigned)x) << 16); }
__device__ __forceinline__ u16 f2b(float f) {
    unsigned u = __float_as_uint(f);
    return (u16)((u + 0x7fffu + ((u >> 16) & 1u)) >> 16);   // RNE
}

#define GLOAD_LDS(g, l) __builtin_amdgcn_global_load_lds( \
    (const __attribute__((address_space(1))) void*)(g),    \
    (__attribute__((address_space(3))) void*)(l), 16, 0, 0)
#define BAR()  __builtin_amdgcn_s_barrier()
#define VM4()  asm volatile("s_waitcnt vmcnt(4)" ::: "memory")
#define VM0()  asm volatile("s_waitcnt vmcnt(0)" ::: "memory")

// ---------------- LayerNorm fp32 -> per-row int8 + scale ----------------
__global__ __launch_bounds__(256) void ln_q8(const float* __restrict__ x,
    const float* __restrict__ w, const float* __restrict__ b,
    i8* __restrict__ outq, float* __restrict__ sA)
{
    __shared__ float sh[8];
    int row = blockIdx.x;
    const float* xr = x + (size_t)row * Cv;
    float vals[3];
    float s = 0.f, s2 = 0.f;
#pragma unroll
    for (int i = 0; i < 3; i++) {
        float t = xr[threadIdx.x + 256 * i];
        vals[i] = t; s += t; s2 += t * t;
    }
#pragma unroll
    for (int off = 32; off > 0; off >>= 1) {
        s  += __shfl_down(s, off);
        s2 += __shfl_down(s2, off);
    }
    int wid = threadIdx.x >> 6;
    if ((threadIdx.x & 63) == 0) { sh[wid] = s; sh[4 + wid] = s2; }
    __syncthreads();
    if (threadIdx.x == 0) {
        sh[0] = sh[0] + sh[1] + sh[2] + sh[3];
        sh[4] = sh[4] + sh[5] + sh[6] + sh[7];
    }
    __syncthreads();
    float mean = sh[0] * (1.f / Cv);
    float var  = sh[4] * (1.f / Cv) - mean * mean;
    float rstd = rsqrtf(var + 1e-5f);
    float nv[3], am = 0.f;
#pragma unroll
    for (int i = 0; i < 3; i++) {
        int j = threadIdx.x + 256 * i;
        nv[i] = (vals[i] - mean) * rstd * w[j] + b[j];
        am = fmaxf(am, fabsf(nv[i]));
    }
#pragma unroll
    for (int off = 32; off > 0; off >>= 1) am = fmaxf(am, __shfl_xor(am, off));
    __syncthreads();
    if ((threadIdx.x & 63) == 0) sh[wid] = am;
    __syncthreads();
    am = fmaxf(fmaxf(sh[0], sh[1]), fmaxf(sh[2], sh[3]));
    am = fmaxf(am, 1e-20f);
    float inv = 127.f / am;
    if (threadIdx.x == 0) sA[row] = am * (1.f / 127.f);
    i8* orow = outq + (size_t)row * Cv;
#pragma unroll
    for (int i = 0; i < 3; i++)
        orow[threadIdx.x + 256 * i] = (i8)(int)rintf(nv[i] * inv);
}

// ---------------- per-row weight quantization: fp32 [rows x K] -> i8 + scale ----------------
__global__ __launch_bounds__(256) void quant_w(const float* __restrict__ src,
    i8* __restrict__ dst, float* __restrict__ sW, int K)
{
    __shared__ float sh[4];
    int row = blockIdx.x;
    const float* sr_ = src + (size_t)row * K;
    i8* dr = dst + (size_t)row * K;
    float am = 0.f;
    for (int j = threadIdx.x; j < K; j += 256) am = fmaxf(am, fabsf(sr_[j]));
#pragma unroll
    for (int off = 32; off > 0; off >>= 1) am = fmaxf(am, __shfl_xor(am, off));
    int wid = threadIdx.x >> 6;
    if ((threadIdx.x & 63) == 0) sh[wid] = am;
    __syncthreads();
    am = fmaxf(fmaxf(sh[0], sh[1]), fmaxf(sh[2], sh[3]));
    am = fmaxf(am, 1e-20f);
    float inv = 127.f / am;
    if (threadIdx.x == 0) sW[row] = am * (1.f / 127.f);
    for (int j = threadIdx.x; j < K; j += 256) dr[j] = (i8)(int)rintf(sr_[j] * inv);
}

// ---------------- per-row bf16 -> i8 quantization (for kf) ----------------
__global__ __launch_bounds__(256) void quant_bf(const u16* __restrict__ src,
    i8* __restrict__ dst, float* __restrict__ sA, int K)
{
    __shared__ float sh[4];
    int row = blockIdx.x;
    const u16* sr_ = src + (size_t)row * K;
    i8* dr = dst + (size_t)row * K;
    float am = 0.f;
    for (int j = threadIdx.x; j < K; j += 256) am = fmaxf(am, fabsf(b2f(sr_[j])));
#pragma unroll
    for (int off = 32; off > 0; off >>= 1) am = fmaxf(am, __shfl_xor(am, off));
    int wid = threadIdx.x >> 6;
    if ((threadIdx.x & 63) == 0) sh[wid] = am;
    __syncthreads();
    am = fmaxf(fmaxf(sh[0], sh[1]), fmaxf(sh[2], sh[3]));
    am = fmaxf(am, 1e-20f);
    float inv = 127.f / am;
    if (threadIdx.x == 0) sA[row] = am * (1.f / 127.f);
    for (int j = threadIdx.x; j < K; j += 256) dr[j] = (i8)(int)rintf(b2f(sr_[j]) * inv);
}

// ---------------- fp32 -> bf16 weight conversion (Wo only) ----------------
__global__ __launch_bounds__(256) void cvt_f2b(const float* __restrict__ s,
    u16* __restrict__ d, int n4)
{
    int i = blockIdx.x * 256 + threadIdx.x;
    if (i < n4) {
        float4 f = *(const float4*)(s + (size_t)i * 4);
        uint2 p;
        p.x = (unsigned)f2b(f.x) | ((unsigned)f2b(f.y) << 16);
        p.y = (unsigned)f2b(f.z) | ((unsigned)f2b(f.w) << 16);
        *(uint2*)(d + (size_t)i * 4) = p;
    }
}

// ---------------- int8 MFMA GEMM, 2 blocks/CU: out = (A@W^T) * sA[r] * sW[c] ----------
// BM=BN=128, BK=128 (i8), 256 thr = 4 waves (2x2); per-wave C = 64x64 (4x4 frags),
// mfma_i32_16x16x64_i8 (K=64/instr). LDS: 2 bufs x 4 planes {A_k0,A_k1,B_k0,B_k1}
// x [128 rows x 64 i8] = 64 KiB -> 2 blocks/CU. Same schedule/swizzle/vmcnt ledger as
// the round-7 bf16 kernel (identical 64B-row plane geometry). K % 128 == 0.
// Grid: 1-D nb = (M/128)*ny, nb%8==0; XCD-chunk + y-fast decode.
// EPI 0: bf16 out (sigmoid when col>=sigoff); 3: f32 out = e0 + b2f(e1)*r;
// EPI 5: dual: col<sigoff -> relu(r)^2 bf16 to outv(ldc); else sigmoid bf16 out2(ldc2).
template<int EPI>
__global__ __launch_bounds__(256, 2) void gemm128q(const i8* __restrict__ A,
    const i8* __restrict__ W, void* __restrict__ outv, void* __restrict__ out2,
    int K, int lda, int ldw, int ldc, int ldc2, int ny, int sigoff,
    const float* __restrict__ sA, const float* __restrict__ sW,
    const float* __restrict__ e0, const u16* __restrict__ e1)
{
    __shared__ i8 lds[2][4][8192];             // [buf][plane][128*64]
    const int tid = threadIdx.x;
    const int wv = tid >> 6, l = tid & 63;
    const int nb = (int)gridDim.x, bid = (int)blockIdx.x;
    const int q = nb >> 3;
    const int sw = (bid & 7) * q + (bid >> 3);
    const int bm = (sw / ny) * 128, bn = (sw % ny) * 128;
    const int wr = wv >> 1, wc = wv & 1;
    // staging: lane covers row (l>>2) of 32-row wave slab, 16B chunk (l&3), swizzled src
    const int row0 = wv * 32 + (l >> 2);
    const int scol = ((l & 3) ^ ((l >> 3) & 3)) << 4;        // i8 units
    const i8* srcA = A + (size_t)(bm + row0) * lda + scol;
    const i8* srcB = W + (size_t)(bn + row0) * ldw + scol;
#define STG(buf, kt, kh) { \
    const size_t kc = (size_t)(kt) * 128 + (size_t)(kh) * 64; \
    GLOAD_LDS(srcA + kc,                    &lds[buf][kh][wv * 2048]); \
    GLOAD_LDS(srcA + kc + (size_t)16 * lda, &lds[buf][kh][wv * 2048 + 1024]); \
    GLOAD_LDS(srcB + kc,                    &lds[buf][2 + (kh)][wv * 2048]); \
    GLOAD_LDS(srcB + kc + (size_t)16 * ldw, &lds[buf][2 + (kh)][wv * 2048 + 1024]); }
    // fragment reads: lane row = (l&15)+16m, k-base (l>>4)*16B, swizzled slot
    const int swz = ((l >> 4) ^ ((l >> 1) & 3)) << 4;
    const int ab  = (wr * 64 + (l & 15)) * 64 + swz;
    const int bb  = (wc * 64 + (l & 15)) * 64 + swz;
#define RD(kh, pbuf) { \
    _Pragma("unroll") \
    for (int i = 0; i < 4; i++) { \
        a4[i] = *(const i4v*)&lds[pbuf][kh][ab + i * 1024]; \
        b4[i] = *(const i4v*)&lds[pbuf][2 + (kh)][bb + i * 1024]; } }
#define MF() { \
    __builtin_amdgcn_s_setprio(1); \
    _Pragma("unroll") \
    for (int mm = 0; mm < 4; mm++) \
        _Pragma("unroll") \
        for (int nn = 0; nn < 4; nn++) \
            acc[mm][nn] = __builtin_amdgcn_mfma_i32_16x16x64_i8( \
                a4[mm], b4[nn], acc[mm][nn], 0, 0, 0); \
    __builtin_amdgcn_s_setprio(0); }

    i4v acc[4][4] = {};
    const int NKT = K >> 7;
    STG(0, 0, 0); STG(0, 0, 1);
    VM4();
    BAR();
    for (int t = 0; t < NKT; ++t) {
        const int p = t & 1;
        const bool st = (t + 1) < NKT;
        i4v a4[4], b4[4];
        RD(0, p);
        if (st) STG(p ^ 1, t + 1, 0);
        BAR();
        MF();
        if (st) VM4(); else VM0();
        BAR();
        RD(1, p);
        if (st) STG(p ^ 1, t + 1, 1);
        BAR();
        MF();
        if (st) VM4();
        BAR();
    }
#undef STG
#undef RD
#undef MF
    // epilogue: C row=(lane>>4)*4+i, col=lane&15 per 16x16 fragment
    const int r0 = bm + wr * 64 + ((l >> 4) << 2);
    const int c0 = bn + wc * 64 + (l & 15);
    float sw4[4];
#pragma unroll
    for (int nf = 0; nf < 4; nf++) sw4[nf] = sW[c0 + nf * 16];
#pragma unroll
    for (int mf = 0; mf < 4; mf++)
#pragma unroll
        for (int i = 0; i < 4; i++) {
            const int row = r0 + mf * 16 + i;
            const float sar = sA[row];
#pragma unroll
            for (int nf = 0; nf < 4; nf++) {
                const int col = c0 + nf * 16;
                float r = (float)acc[mf][nf][i] * sar * sw4[nf];
                if (EPI == 0) {
                    if (col >= sigoff) r = 1.f / (1.f + __expf(-r));
                    ((u16*)outv)[(size_t)row * ldc + col] = f2b(r);
                } else if (EPI == 3) {
                    size_t o = (size_t)row * ldc + col;
                    ((float*)outv)[o] = fmaf(b2f(e1[o]), r, e0[o]);
                } else if (EPI == 5) {
                    if (col < sigoff) {
                        float t2 = fmaxf(r, 0.f);
                        ((u16*)outv)[(size_t)row * ldc + col] = f2b(t2 * t2);
                    } else {
                        float sg = 1.f / (1.f + __expf(-r));
                        ((u16*)out2)[(size_t)row * ldc2 + (col - sigoff)] = f2b(sg);
                    }
                }
            }
        }
}

// ---------------- bf16 MFMA GEMM (round-7, kept for Wo): out = A @ W^T ----------------
template<int EPI>
__global__ __launch_bounds__(256, 2) void gemm128(const u16* __restrict__ A,
    const u16* __restrict__ W, void* __restrict__ outv,
    int K, int lda, int ldw, int ldc, int ny,
    const float* __restrict__ e0)
{
    __shared__ u16 lds[2][4][4096];
    const int tid = threadIdx.x;
    const int wv = tid >> 6, l = tid & 63;
    const int nb = (int)gridDim.x, bid = (int)blockIdx.x;
    const int q = nb >> 3;
    const int sw = (bid & 7) * q + (bid >> 3);
    const int bm = (sw / ny) * 128, bn = (sw % ny) * 128;
    const int wr = wv >> 1, wc = wv & 1;
    const int row0 = wv * 32 + (l >> 2);
    const int scol = ((l & 3) ^ ((l >> 3) & 3)) << 3;
    const u16* srcA = A + (size_t)(bm + row0) * lda + scol;
    const u16* srcB = W + (size_t)(bn + row0) * ldw + scol;
#define STG(buf, kt, kh) { \
    const size_t kc = (size_t)(kt) * 64 + (size_t)(kh) * 32; \
    GLOAD_LDS(srcA + kc,                    &lds[buf][kh][wv * 1024]); \
    GLOAD_LDS(srcA + kc + (size_t)16 * lda, &lds[buf][kh][wv * 1024 + 512]); \
    GLOAD_LDS(srcB + kc,                    &lds[buf][2 + (kh)][wv * 1024]); \
    GLOAD_LDS(srcB + kc + (size_t)16 * ldw, &lds[buf][2 + (kh)][wv * 1024 + 512]); }
    const int swz = ((l >> 4) ^ ((l >> 1) & 3)) << 3;
    const int ab  = (wr * 64 + (l & 15)) * 32 + swz;
    const int bb  = (wc * 64 + (l & 15)) * 32 + swz;
#define RD(kh, pbuf) { \
    _Pragma("unroll") \
    for (int i = 0; i < 4; i++) { \
        a4[i] = *(const s8v*)&lds[pbuf][kh][ab + i * 512]; \
        b4[i] = *(const s8v*)&lds[pbuf][2 + (kh)][bb + i * 512]; } }
#define MF() { \
    __builtin_amdgcn_s_setprio(1); \
    _Pragma("unroll") \
    for (int mm = 0; mm < 4; mm++) \
        _Pragma("unroll") \
        for (int nn = 0; nn < 4; nn++) \
            acc[mm][nn] = __builtin_amdgcn_mfma_f32_16x16x32_bf16( \
                a4[mm], b4[nn], acc[mm][nn], 0, 0, 0); \
    __builtin_amdgcn_s_setprio(0); }

    f4v acc[4][4] = {};
    const int NKT = K >> 6;
    STG(0, 0, 0); STG(0, 0, 1);
    VM4();
    BAR();
    for (int t = 0; t < NKT; ++t) {
        const int p = t & 1;
        const bool st = (t + 1) < NKT;
        s8v a4[4], b4[4];
        RD(0, p);
        if (st) STG(p ^ 1, t + 1, 0);
        BAR();
        MF();
        if (st) VM4(); else VM0();
        BAR();
        RD(1, p);
        if (st) STG(p ^ 1, t + 1, 1);
        BAR();
        MF();
        if (st) VM4();
        BAR();
    }
#undef STG
#undef RD
#undef MF
    const int r0 = bm + wr * 64 + ((l >> 4) << 2);
    const int c0 = bn + wc * 64 + (l & 15);
#pragma unroll
    for (int mf = 0; mf < 4; mf++)
#pragma unroll
        for (int nf = 0; nf < 4; nf++)
#pragma unroll
            for (int i = 0; i < 4; i++) {
                const int row = r0 + mf * 16 + i;
                const int col = c0 + nf * 16;
                size_t o = (size_t)row * ldc + col;
                if (EPI == 4) ((float*)outv)[o] = e0[o] + acc[mf][nf][i];
            }
}

// ---------------- WKV helpers ----------------
__device__ __forceinline__ void wkv_step(float& a, float& b, float& m,
                                         float w, float kt, float vt)
{
    float mm = fmaxf(m + w, kt);
    float e1 = __expf(m + w - mm);
    float e2 = __expf(kt - mm);
    a = e1 * a + e2 * vt;
    b = e1 * b + e2;
    m = mm;
}
__device__ __forceinline__ void wkv_merge(float& a, float& b, float& m,
                                          float shift, float a2, float b2, float m2)
{
    float ms = m + shift;
    float mm = fmaxf(ms, m2);
    float e1 = __expf(ms - mm);
    float e2 = __expf(m2 - mm);
    a = e1 * a + e2 * a2;
    b = e1 * b + e2 * b2;
    m = mm;
}

// ---------------- WKV pass 1 ----------------
__global__ __launch_bounds__(256) void wkv_pass1(const u16* __restrict__ kvs,
    const float* __restrict__ decay, float* __restrict__ sums)
{
    int e = blockIdx.x * 256 + threadIdx.x;
    int idx = e % BC, ci = e / BC;
    int b = idx / Cv, c = idx % Cv;
    float w = decay[c] * (1.f / (float)Tv);
    size_t base = ((size_t)b * Tv + (size_t)ci * Lc) * KVS + c;
    const size_t P = (size_t)NCHK * BC;
    size_t so = (size_t)ci * BC + idx;
    float a = 0.f, bb = 0.f, m = -1e38f;
    for (int t = 0; t < Lc; t++) {
        size_t off = base + (size_t)t * KVS;
        wkv_step(a, bb, m, w, b2f(kvs[off]), b2f(kvs[off + 768]));
    }
    sums[0 * P + so] = a; sums[1 * P + so] = bb; sums[2 * P + so] = m;
    a = 0.f; bb = 0.f; m = -1e38f;
    for (int t = Lc - 1; t >= 0; t--) {
        size_t off = base + (size_t)t * KVS;
        wkv_step(a, bb, m, w, b2f(kvs[off]), b2f(kvs[off + 768]));
    }
    sums[3 * P + so] = a; sums[4 * P + so] = bb; sums[5 * P + so] = m;
}

// ---------------- WKV pass 2 ----------------
__global__ __launch_bounds__(256) void wkv_pass2(const float* __restrict__ decay,
    const float* __restrict__ sums, float* __restrict__ chks)
{
    int idx = blockIdx.x * 256 + threadIdx.x;
    int c = idx % Cv;
    float shift = decay[c] * (1.f / (float)Tv) * (float)Lc;
    const size_t P = (size_t)NCHK * BC;
    float a = 0.f, bb = 0.f, m = -1e38f;
    for (int ci = 0; ci < NCHK; ci++) {
        size_t so = (size_t)ci * BC + idx;
        chks[0 * P + so] = a; chks[1 * P + so] = bb; chks[2 * P + so] = m;
        wkv_merge(a, bb, m, shift, sums[0 * P + so], sums[1 * P + so], sums[2 * P + so]);
    }
    a = 0.f; bb = 0.f; m = -1e38f;
    for (int ci = NCHK - 1; ci >= 0; ci--) {
        size_t so = (size_t)ci * BC + idx;
        chks[3 * P + so] = a; chks[4 * P + so] = bb; chks[5 * P + so] = m;
        wkv_merge(a, bb, m, shift, sums[3 * P + so], sums[4 * P + so], sums[5 * P + so]);
    }
}

// ---------------- WKV pass 3 ----------------
__global__ __launch_bounds__(256) void wkv_pass3(u16* __restrict__ kvs,
    const float* __restrict__ decay, const float* __restrict__ first,
    const float* __restrict__ chks)
{
    int e = blockIdx.x * 256 + threadIdx.x;
    int idx = e % BC, ci = e / BC;
    int b = idx / Cv, c = idx % Cv;
    float w = decay[c] * (1.f / (float)Tv);
    float u = first[c] * (1.f / (float)Tv);
    const size_t P = (size_t)NCHK * BC;
    size_t so = (size_t)ci * BC + idx;
    size_t base = ((size_t)b * Tv + (size_t)ci * Lc) * KVS + c;
    float sa = chks[3 * P + so], sb2 = chks[4 * P + so], sm = chks[5 * P + so];
    float Ba[8], Bb[8], Bm[8];
#pragma unroll
    for (int si = 7; si >= 0; si--) {
        Ba[si] = sa; Bb[si] = sb2; Bm[si] = sm;
        for (int j = 15; j >= 0; j--) {
            size_t off = base + (size_t)(si * 16 + j) * KVS;
            wkv_step(sa, sb2, sm, w, b2f(kvs[off]), b2f(kvs[off + 768]));
        }
    }
    float fa = chks[0 * P + so], fb2 = chks[1 * P + so], fm = chks[2 * P + so];
#pragma unroll
    for (int si = 0; si < 8; si++) {
        float lk[16], lv[16], la[16], lb[16], lm[16];
        float ta = Ba[si], tb = Bb[si], tm = Bm[si];
#pragma unroll
        for (int j = 15; j >= 0; j--) {
            size_t off = base + (size_t)(si * 16 + j) * KVS;
            lk[j] = b2f(kvs[off]); lv[j] = b2f(kvs[off + 768]);
            la[j] = ta; lb[j] = tb; lm[j] = tm;
            wkv_step(ta, tb, tm, w, lk[j], lv[j]);
        }
#pragma unroll
        for (int j = 0; j < 16; j++) {
            float kk = lk[j] + u;
            float M  = fmaxf(fmaxf(fm, lm[j]), kk);
            float ef = __expf(fm - M);
            float eb = __expf(lm[j] - M);
            float ec = __expf(kk - M);
            float num = ef * fa + eb * la[j] + ec * lv[j];
            float den = ef * fb2 + eb * lb[j] + ec;
            size_t off = base + (size_t)(si * 16 + j) * KVS;
            kvs[off] = f2b(b2f(kvs[off + 1536]) * (num / den));  // y' = sr * y
            wkv_step(fa, fb2, fm, w, lk[j], lv[j]);
        }
    }
}

__global__ __launch_bounds__(256) void fill_signal(float* __restrict__ out, int n, float val)
{
    int i = blockIdx.x * 256 + threadIdx.x;
    if (i < n) out[i] = val;
}

extern "C" void kernel_launch(void* const* d_in, const int* in_sizes, int n_in,
                              void* d_out, int out_size, void* d_ws, size_t ws_size,
                              hipStream_t stream)
{
    const float* x     = (const float*)d_in[0];
    const float* ln1_w = (const float*)d_in[1];
    const float* ln1_b = (const float*)d_in[2];
    const float* ln2_w = (const float*)d_in[3];
    const float* ln2_b = (const float*)d_in[4];
    const float* decay = (const float*)d_in[5];
    const float* first = (const float*)d_in[6];
    const float* Wk_a  = (const float*)d_in[7];
    const float* Wv_a  = (const float*)d_in[8];
    const float* Wr_a  = (const float*)d_in[9];
    const float* Wo_a  = (const float*)d_in[10];
    const float* Wk_f  = (const float*)d_in[11];
    const float* Wv_f  = (const float*)d_in[12];
    const float* Wr_f  = (const float*)d_in[13];
    float* out = (float*)d_out;

    const size_t NCe = (size_t)BT * Cv;        // 12,582,912
    const size_t CC  = (size_t)Cv * Cv;
    const size_t HC  = (size_t)Hv * Cv;
    const size_t SUM = (size_t)6 * NCHK * BC;
    const int    MCH = 4096;                   // FFN chunk rows (4 chunks)

    char* p = (char*)d_ws;
    i8*  h8    = (i8*)p;            p += NCe;                 // h_i8 / h2_i8 (reused)
    u16* kvs   = (u16*)p;           p += 3 * NCe * 2;         // k|v|sr bf16 (stride 2304)
    float* x1  = (float*)p;         p += NCe * 4;             // fp32 x after attention
    i8*  wKVR  = (i8*)p;            p += (size_t)KVS * Cv;    // [Wk;Wv;Wr] i8
    i8*  wUG   = (i8*)p;            p += (size_t)(Hv + Cv) * Cv; // [Wk_f;Wr_f] i8
    i8*  wVf8  = (i8*)p;            p += (size_t)Cv * Hv;     // Wv_f i8
    u16* wOa   = (u16*)p;           p += CC * 2;              // Wo bf16
    float* sums = (float*)p;        p += SUM * 4;
    float* chks = (float*)p;        p += SUM * 4;
    float* sAct = (float*)p;        p += (size_t)BT * 4;      // row scales for h / h2
    float* sKf  = (float*)p;        p += (size_t)MCH * 4;     // row scales for kf chunk
    float* sWk  = (float*)p;        p += (size_t)KVS * 4;
    float* sWu  = (float*)p;        p += (size_t)(Hv + Cv) * 4;
    float* sWv  = (float*)p;        p += (size_t)Cv * 4;
    size_t need = (size_t)(p - (char*)d_ws);

    if (ws_size < need) {
        fill_signal<<<(int)((NCe + 255) / 256), 256, 0, stream>>>(out, (int)NCe, (float)(ws_size >> 20));
        return;
    }

    // overlays into dead kvs region (after Wo-GEMM):
    u16* gate  = kvs;                          // BT x 768 bf16
    u16* kf_c  = kvs + NCe;                    // MCH x 3072 bf16 (chunk)
    i8*  kf_8  = (i8*)(kvs + 2 * NCe);         // MCH x 3072 i8 (chunk)

    dim3 blk(256);
    // weight quantization (i8 per-output-channel) + Wo bf16
    quant_w<<<Cv, blk, 0, stream>>>(Wk_a, wKVR,               sWk,            Cv);
    quant_w<<<Cv, blk, 0, stream>>>(Wv_a, wKVR + CC,          sWk + Cv,       Cv);
    quant_w<<<Cv, blk, 0, stream>>>(Wr_a, wKVR + 2 * CC,      sWk + 2 * Cv,   Cv);
    quant_w<<<Hv, blk, 0, stream>>>(Wk_f, wUG,                sWu,            Cv);
    quant_w<<<Cv, blk, 0, stream>>>(Wr_f, wUG + HC,           sWu + Hv,       Cv);
    quant_w<<<Cv, blk, 0, stream>>>(Wv_f, wVf8,               sWv,            Hv);
    cvt_f2b<<<(int)(CC / 4 + 255) / 256, blk, 0, stream>>>(Wo_a, wOa, (int)(CC / 4));

    // 1. h = LN1(x) -> i8 + row scales
    ln_q8<<<BT, blk, 0, stream>>>(x, ln1_w, ln1_b, h8, sAct);
    // 2. fused [k|v|sr] = h @ [Wk;Wv;Wr]^T (i8), sigmoid cols >= 1536. grid 128*18=2304
    gemm128q<0><<<dim3((BT / 128) * (KVS / 128)), blk, 0, stream>>>(
        h8, wKVR, kvs, nullptr, Cv, Cv, Cv, KVS, 0, KVS / 128, 1536,
        sAct, sWk, nullptr, nullptr);
    // 3. bidirectional WKV; y*sr written over k slot
    wkv_pass1<<<(BC * NCHK) / 256, blk, 0, stream>>>(kvs, decay, sums);
    wkv_pass2<<<BC / 256, blk, 0, stream>>>(decay, sums, chks);
    wkv_pass3<<<(BC * NCHK) / 256, blk, 0, stream>>>(kvs, decay, first, chks);
    // 4. x1 = x + (sr*y) @ Wo^T (bf16). grid 128*6=768
    gemm128<4><<<dim3((BT / 128) * (Cv / 128)), blk, 0, stream>>>(
        kvs, wOa, x1, Cv, KVS, Cv, Cv, Cv / 128, x);
    // 5. h2 = LN2(x1) -> i8 + row scales (h dead; reuse buffers)
    ln_q8<<<BT, blk, 0, stream>>>(x1, ln2_w, ln2_b, h8, sAct);
    // 6. FFN in 4 chunks of 4096 rows: fused up+gate (i8) -> quant kf -> down (i8)
    for (int j = 0; j < 4; j++) {
        size_t ro = (size_t)j * MCH;
        gemm128q<5><<<dim3((MCH / 128) * ((Hv + Cv) / 128)), blk, 0, stream>>>(
            h8 + ro * Cv, wUG, kf_c, gate + ro * Cv, Cv, Cv, Cv, Hv, Cv,
            (Hv + Cv) / 128, Hv, sAct + ro, sWu, nullptr, nullptr);
        quant_bf<<<MCH, blk, 0, stream>>>(kf_c, kf_8, sKf, Hv);
        gemm128q<3><<<dim3((MCH / 128) * (Cv / 128)), blk, 0, stream>>>(
            kf_8, wVf8, out + ro * Cv, nullptr, Hv, Hv, Hv, Cv, 0, Cv / 128, 0,
            sKf, sWv, x1 + ro * Cv, gate + ro * Cv);
    }
}

// Round 9
// 486.527 us; speedup vs baseline: 1.1135x; 1.1135x over previous
//
#include <hip/hip_runtime.h>
#include <math.h>

typedef unsigned short u16;
typedef signed char i8;
typedef short s8v __attribute__((ext_vector_type(8)));   // 8 bf16 (4 VGPRs)
typedef float f4v __attribute__((ext_vector_type(4)));   // 4 fp32 acc
typedef int   i4v __attribute__((ext_vector_type(4)));   // 4 i32 (16 i8 / i32 acc)

constexpr int Bv = 8, Tv = 2048, Cv = 768, Hv = 3072;
constexpr int BT = Bv * Tv;       // 16384 tokens
constexpr int BC = Bv * Cv;       // 6144 channels
constexpr int Lc = 32;            // WKV chunk length
constexpr int NCHK = Tv / Lc;     // 64 chunks
constexpr int SI = Lc / 16;       // 2 sub-chunks
constexpr int KVS = 2304;         // fused k|v|sr row stride

__device__ __forceinline__ float b2f(u16 x) { return __uint_as_float(((unsigned)x) << 16); }
__device__ __forceinline__ u16 f2b(float f) {
    unsigned u = __float_as_uint(f);
    return (u16)((u + 0x7fffu + ((u >> 16) & 1u)) >> 16);   // RNE
}

#define GLOAD_LDS(g, l) __builtin_amdgcn_global_load_lds( \
    (const __attribute__((address_space(1))) void*)(g),    \
    (__attribute__((address_space(3))) void*)(l), 16, 0, 0)
#define BAR()  __builtin_amdgcn_s_barrier()
#define VM4()  asm volatile("s_waitcnt vmcnt(4)" ::: "memory")
#define VM0()  asm volatile("s_waitcnt vmcnt(0)" ::: "memory")

// ---------------- LayerNorm fp32 -> per-row int8 + scale ----------------
__global__ __launch_bounds__(256) void ln_q8(const float* __restrict__ x,
    const float* __restrict__ w, const float* __restrict__ b,
    i8* __restrict__ outq, float* __restrict__ sA)
{
    __shared__ float sh[8];
    int row = blockIdx.x;
    const float* xr = x + (size_t)row * Cv;
    float vals[3];
    float s = 0.f, s2 = 0.f;
#pragma unroll
    for (int i = 0; i < 3; i++) {
        float t = xr[threadIdx.x + 256 * i];
        vals[i] = t; s += t; s2 += t * t;
    }
#pragma unroll
    for (int off = 32; off > 0; off >>= 1) {
        s  += __shfl_down(s, off);
        s2 += __shfl_down(s2, off);
    }
    int wid = threadIdx.x >> 6;
    if ((threadIdx.x & 63) == 0) { sh[wid] = s; sh[4 + wid] = s2; }
    __syncthreads();
    if (threadIdx.x == 0) {
        sh[0] = sh[0] + sh[1] + sh[2] + sh[3];
        sh[4] = sh[4] + sh[5] + sh[6] + sh[7];
    }
    __syncthreads();
    float mean = sh[0] * (1.f / Cv);
    float var  = sh[4] * (1.f / Cv) - mean * mean;
    float rstd = rsqrtf(var + 1e-5f);
    float nv[3], am = 0.f;
#pragma unroll
    for (int i = 0; i < 3; i++) {
        int j = threadIdx.x + 256 * i;
        nv[i] = (vals[i] - mean) * rstd * w[j] + b[j];
        am = fmaxf(am, fabsf(nv[i]));
    }
#pragma unroll
    for (int off = 32; off > 0; off >>= 1) am = fmaxf(am, __shfl_xor(am, off));
    __syncthreads();
    if ((threadIdx.x & 63) == 0) sh[wid] = am;
    __syncthreads();
    am = fmaxf(fmaxf(sh[0], sh[1]), fmaxf(sh[2], sh[3]));
    am = fmaxf(am, 1e-20f);
    float inv = 127.f / am;
    if (threadIdx.x == 0) sA[row] = am * (1.f / 127.f);
    i8* orow = outq + (size_t)row * Cv;
#pragma unroll
    for (int i = 0; i < 3; i++)
        orow[threadIdx.x + 256 * i] = (i8)(int)rintf(nv[i] * inv);
}

// ---------------- per-row weight quantization (up to 3 stacked sources, same K) ------
__global__ __launch_bounds__(256) void quant_w3(const float* __restrict__ s0,
    const float* __restrict__ s1, const float* __restrict__ s2,
    int n0, int n1, i8* __restrict__ dst, float* __restrict__ sW, int K)
{
    __shared__ float sh[4];
    int row = blockIdx.x;
    const float* src = (row < n0) ? (s0 + (size_t)row * K)
                     : (row < n0 + n1) ? (s1 + (size_t)(row - n0) * K)
                     : (s2 + (size_t)(row - n0 - n1) * K);
    i8* dr = dst + (size_t)row * K;
    float am = 0.f;
    for (int j = threadIdx.x; j < K; j += 256) am = fmaxf(am, fabsf(src[j]));
#pragma unroll
    for (int off = 32; off > 0; off >>= 1) am = fmaxf(am, __shfl_xor(am, off));
    int wid = threadIdx.x >> 6;
    if ((threadIdx.x & 63) == 0) sh[wid] = am;
    __syncthreads();
    am = fmaxf(fmaxf(sh[0], sh[1]), fmaxf(sh[2], sh[3]));
    am = fmaxf(am, 1e-20f);
    float inv = 127.f / am;
    if (threadIdx.x == 0) sW[row] = am * (1.f / 127.f);
    for (int j = threadIdx.x; j < K; j += 256) dr[j] = (i8)(int)rintf(src[j] * inv);
}

// ---------------- per-row bf16 -> i8 quantization (for kf) ----------------
__global__ __launch_bounds__(256) void quant_bf(const u16* __restrict__ src,
    i8* __restrict__ dst, float* __restrict__ sA, int K)
{
    __shared__ float sh[4];
    int row = blockIdx.x;
    const u16* sr_ = src + (size_t)row * K;
    i8* dr = dst + (size_t)row * K;
    float am = 0.f;
    for (int j = threadIdx.x; j < K; j += 256) am = fmaxf(am, fabsf(b2f(sr_[j])));
#pragma unroll
    for (int off = 32; off > 0; off >>= 1) am = fmaxf(am, __shfl_xor(am, off));
    int wid = threadIdx.x >> 6;
    if ((threadIdx.x & 63) == 0) sh[wid] = am;
    __syncthreads();
    am = fmaxf(fmaxf(sh[0], sh[1]), fmaxf(sh[2], sh[3]));
    am = fmaxf(am, 1e-20f);
    float inv = 127.f / am;
    if (threadIdx.x == 0) sA[row] = am * (1.f / 127.f);
    for (int j = threadIdx.x; j < K; j += 256) dr[j] = (i8)(int)rintf(b2f(sr_[j]) * inv);
}

// ---------------- fp32 -> bf16 weight conversion (Wo only) ----------------
__global__ __launch_bounds__(256) void cvt_f2b(const float* __restrict__ s,
    u16* __restrict__ d, int n4)
{
    int i = blockIdx.x * 256 + threadIdx.x;
    if (i < n4) {
        float4 f = *(const float4*)(s + (size_t)i * 4);
        uint2 p;
        p.x = (unsigned)f2b(f.x) | ((unsigned)f2b(f.y) << 16);
        p.y = (unsigned)f2b(f.z) | ((unsigned)f2b(f.w) << 16);
        *(uint2*)(d + (size_t)i * 4) = p;
    }
}

// ---------------- int8 MFMA GEMM, 2 blocks/CU (round-8 proven) ----------
template<int EPI>
__global__ __launch_bounds__(256, 2) void gemm128q(const i8* __restrict__ A,
    const i8* __restrict__ W, void* __restrict__ outv, void* __restrict__ out2,
    int K, int lda, int ldw, int ldc, int ldc2, int ny, int sigoff,
    const float* __restrict__ sA, const float* __restrict__ sW,
    const float* __restrict__ e0, const u16* __restrict__ e1)
{
    __shared__ i8 lds[2][4][8192];             // [buf][plane][128*64]
    const int tid = threadIdx.x;
    const int wv = tid >> 6, l = tid & 63;
    const int nb = (int)gridDim.x, bid = (int)blockIdx.x;
    const int q = nb >> 3;
    const int sw = (bid & 7) * q + (bid >> 3);
    const int bm = (sw / ny) * 128, bn = (sw % ny) * 128;
    const int wr = wv >> 1, wc = wv & 1;
    const int row0 = wv * 32 + (l >> 2);
    const int scol = ((l & 3) ^ ((l >> 3) & 3)) << 4;        // i8 units
    const i8* srcA = A + (size_t)(bm + row0) * lda + scol;
    const i8* srcB = W + (size_t)(bn + row0) * ldw + scol;
#define STG(buf, kt, kh) { \
    const size_t kc = (size_t)(kt) * 128 + (size_t)(kh) * 64; \
    GLOAD_LDS(srcA + kc,                    &lds[buf][kh][wv * 2048]); \
    GLOAD_LDS(srcA + kc + (size_t)16 * lda, &lds[buf][kh][wv * 2048 + 1024]); \
    GLOAD_LDS(srcB + kc,                    &lds[buf][2 + (kh)][wv * 2048]); \
    GLOAD_LDS(srcB + kc + (size_t)16 * ldw, &lds[buf][2 + (kh)][wv * 2048 + 1024]); }
    const int swz = ((l >> 4) ^ ((l >> 1) & 3)) << 4;
    const int ab  = (wr * 64 + (l & 15)) * 64 + swz;
    const int bb  = (wc * 64 + (l & 15)) * 64 + swz;
#define RD(kh, pbuf) { \
    _Pragma("unroll") \
    for (int i = 0; i < 4; i++) { \
        a4[i] = *(const i4v*)&lds[pbuf][kh][ab + i * 1024]; \
        b4[i] = *(const i4v*)&lds[pbuf][2 + (kh)][bb + i * 1024]; } }
#define MF() { \
    __builtin_amdgcn_s_setprio(1); \
    _Pragma("unroll") \
    for (int mm = 0; mm < 4; mm++) \
        _Pragma("unroll") \
        for (int nn = 0; nn < 4; nn++) \
            acc[mm][nn] = __builtin_amdgcn_mfma_i32_16x16x64_i8( \
                a4[mm], b4[nn], acc[mm][nn], 0, 0, 0); \
    __builtin_amdgcn_s_setprio(0); }

    i4v acc[4][4] = {};
    const int NKT = K >> 7;
    STG(0, 0, 0); STG(0, 0, 1);
    VM4();
    BAR();
    for (int t = 0; t < NKT; ++t) {
        const int p = t & 1;
        const bool st = (t + 1) < NKT;
        i4v a4[4], b4[4];
        RD(0, p);
        if (st) STG(p ^ 1, t + 1, 0);
        BAR();
        MF();
        if (st) VM4(); else VM0();
        BAR();
        RD(1, p);
        if (st) STG(p ^ 1, t + 1, 1);
        BAR();
        MF();
        if (st) VM4();
        BAR();
    }
#undef STG
#undef RD
#undef MF
    const int r0 = bm + wr * 64 + ((l >> 4) << 2);
    const int c0 = bn + wc * 64 + (l & 15);
    float sw4[4];
#pragma unroll
    for (int nf = 0; nf < 4; nf++) sw4[nf] = sW[c0 + nf * 16];
#pragma unroll
    for (int mf = 0; mf < 4; mf++)
#pragma unroll
        for (int i = 0; i < 4; i++) {
            const int row = r0 + mf * 16 + i;
            const float sar = sA[row];
#pragma unroll
            for (int nf = 0; nf < 4; nf++) {
                const int col = c0 + nf * 16;
                float r = (float)acc[mf][nf][i] * sar * sw4[nf];
                if (EPI == 0) {
                    if (col >= sigoff) r = 1.f / (1.f + __expf(-r));
                    ((u16*)outv)[(size_t)row * ldc + col] = f2b(r);
                } else if (EPI == 3) {
                    size_t o = (size_t)row * ldc + col;
                    ((float*)outv)[o] = fmaf(b2f(e1[o]), r, e0[o]);
                } else if (EPI == 5) {
                    if (col < sigoff) {
                        float t2 = fmaxf(r, 0.f);
                        ((u16*)outv)[(size_t)row * ldc + col] = f2b(t2 * t2);
                    } else {
                        float sg = 1.f / (1.f + __expf(-r));
                        ((u16*)out2)[(size_t)row * ldc2 + (col - sigoff)] = f2b(sg);
                    }
                }
            }
        }
}

// ---------------- bf16 MFMA GEMM (round-7 proven, kept for Wo) ----------------
template<int EPI>
__global__ __launch_bounds__(256, 2) void gemm128(const u16* __restrict__ A,
    const u16* __restrict__ W, void* __restrict__ outv,
    int K, int lda, int ldw, int ldc, int ny,
    const float* __restrict__ e0)
{
    __shared__ u16 lds[2][4][4096];
    const int tid = threadIdx.x;
    const int wv = tid >> 6, l = tid & 63;
    const int nb = (int)gridDim.x, bid = (int)blockIdx.x;
    const int q = nb >> 3;
    const int sw = (bid & 7) * q + (bid >> 3);
    const int bm = (sw / ny) * 128, bn = (sw % ny) * 128;
    const int wr = wv >> 1, wc = wv & 1;
    const int row0 = wv * 32 + (l >> 2);
    const int scol = ((l & 3) ^ ((l >> 3) & 3)) << 3;
    const u16* srcA = A + (size_t)(bm + row0) * lda + scol;
    const u16* srcB = W + (size_t)(bn + row0) * ldw + scol;
#define STG(buf, kt, kh) { \
    const size_t kc = (size_t)(kt) * 64 + (size_t)(kh) * 32; \
    GLOAD_LDS(srcA + kc,                    &lds[buf][kh][wv * 1024]); \
    GLOAD_LDS(srcA + kc + (size_t)16 * lda, &lds[buf][kh][wv * 1024 + 512]); \
    GLOAD_LDS(srcB + kc,                    &lds[buf][2 + (kh)][wv * 1024]); \
    GLOAD_LDS(srcB + kc + (size_t)16 * ldw, &lds[buf][2 + (kh)][wv * 1024 + 512]); }
    const int swz = ((l >> 4) ^ ((l >> 1) & 3)) << 3;
    const int ab  = (wr * 64 + (l & 15)) * 32 + swz;
    const int bb  = (wc * 64 + (l & 15)) * 32 + swz;
#define RD(kh, pbuf) { \
    _Pragma("unroll") \
    for (int i = 0; i < 4; i++) { \
        a4[i] = *(const s8v*)&lds[pbuf][kh][ab + i * 512]; \
        b4[i] = *(const s8v*)&lds[pbuf][2 + (kh)][bb + i * 512]; } }
#define MF() { \
    __builtin_amdgcn_s_setprio(1); \
    _Pragma("unroll") \
    for (int mm = 0; mm < 4; mm++) \
        _Pragma("unroll") \
        for (int nn = 0; nn < 4; nn++) \
            acc[mm][nn] = __builtin_amdgcn_mfma_f32_16x16x32_bf16( \
                a4[mm], b4[nn], acc[mm][nn], 0, 0, 0); \
    __builtin_amdgcn_s_setprio(0); }

    f4v acc[4][4] = {};
    const int NKT = K >> 6;
    STG(0, 0, 0); STG(0, 0, 1);
    VM4();
    BAR();
    for (int t = 0; t < NKT; ++t) {
        const int p = t & 1;
        const bool st = (t + 1) < NKT;
        s8v a4[4], b4[4];
        RD(0, p);
        if (st) STG(p ^ 1, t + 1, 0);
        BAR();
        MF();
        if (st) VM4(); else VM0();
        BAR();
        RD(1, p);
        if (st) STG(p ^ 1, t + 1, 1);
        BAR();
        MF();
        if (st) VM4();
        BAR();
    }
#undef STG
#undef RD
#undef MF
    const int r0 = bm + wr * 64 + ((l >> 4) << 2);
    const int c0 = bn + wc * 64 + (l & 15);
#pragma unroll
    for (int mf = 0; mf < 4; mf++)
#pragma unroll
        for (int nf = 0; nf < 4; nf++)
#pragma unroll
            for (int i = 0; i < 4; i++) {
                const int row = r0 + mf * 16 + i;
                const int col = c0 + nf * 16;
                size_t o = (size_t)row * ldc + col;
                if (EPI == 4) ((float*)outv)[o] = e0[o] + acc[mf][nf][i];
            }
}

// ---------------- WKV helpers ----------------
__device__ __forceinline__ void wkv_step(float& a, float& b, float& m,
                                         float w, float kt, float vt)
{
    float mm = fmaxf(m + w, kt);
    float e1 = __expf(m + w - mm);
    float e2 = __expf(kt - mm);
    a = e1 * a + e2 * vt;
    b = e1 * b + e2;
    m = mm;
}
__device__ __forceinline__ void wkv_merge(float& a, float& b, float& m,
                                          float shift, float a2, float b2, float m2)
{
    float ms = m + shift;
    float mm = fmaxf(ms, m2);
    float e1 = __expf(ms - mm);
    float e2 = __expf(m2 - mm);
    a = e1 * a + e2 * a2;
    b = e1 * b + e2 * b2;
    m = mm;
}

// ---------------- WKV pass 1: per-chunk summaries, direction-split ----------------
// e in [0, 2*NCHK*BC): dir = e / (NCHK*BC); within: ci = r / BC, idx = r % BC.
__global__ __launch_bounds__(256) void wkv_pass1(const u16* __restrict__ kvs,
    const float* __restrict__ decay, float* __restrict__ sums)
{
    int e = blockIdx.x * 256 + threadIdx.x;
    const int PN = NCHK * BC;
    int dir = e / PN, r = e % PN;
    int idx = r % BC, ci = r / BC;
    int b = idx / Cv, c = idx % Cv;
    float w = decay[c] * (1.f / (float)Tv);
    size_t base = ((size_t)b * Tv + (size_t)ci * Lc) * KVS + c;
    const size_t P = (size_t)NCHK * BC;
    size_t so = (size_t)ci * BC + idx;
    float a = 0.f, bb = 0.f, m = -1e38f;
    if (dir == 0) {
        for (int t = 0; t < Lc; t++) {
            size_t off = base + (size_t)t * KVS;
            wkv_step(a, bb, m, w, b2f(kvs[off]), b2f(kvs[off + 768]));
        }
        sums[0 * P + so] = a; sums[1 * P + so] = bb; sums[2 * P + so] = m;
    } else {
        for (int t = Lc - 1; t >= 0; t--) {
            size_t off = base + (size_t)t * KVS;
            wkv_step(a, bb, m, w, b2f(kvs[off]), b2f(kvs[off + 768]));
        }
        sums[3 * P + so] = a; sums[4 * P + so] = bb; sums[5 * P + so] = m;
    }
}

// ---------------- WKV pass 2: scan chunk summaries, direction-split ----------------
__global__ __launch_bounds__(256) void wkv_pass2(const float* __restrict__ decay,
    const float* __restrict__ sums, float* __restrict__ chks)
{
    int e = blockIdx.x * 256 + threadIdx.x;
    int dir = e / BC, idx = e % BC;
    int c = idx % Cv;
    float shift = decay[c] * (1.f / (float)Tv) * (float)Lc;
    const size_t P = (size_t)NCHK * BC;
    float a = 0.f, bb = 0.f, m = -1e38f;
    if (dir == 0) {
        for (int ci = 0; ci < NCHK; ci++) {
            size_t so = (size_t)ci * BC + idx;
            chks[0 * P + so] = a; chks[1 * P + so] = bb; chks[2 * P + so] = m;
            wkv_merge(a, bb, m, shift, sums[0 * P + so], sums[1 * P + so], sums[2 * P + so]);
        }
    } else {
        for (int ci = NCHK - 1; ci >= 0; ci--) {
            size_t so = (size_t)ci * BC + idx;
            chks[3 * P + so] = a; chks[4 * P + so] = bb; chks[5 * P + so] = m;
            wkv_merge(a, bb, m, shift, sums[3 * P + so], sums[4 * P + so], sums[5 * P + so]);
        }
    }
}

// ---------------- WKV pass 3: per-chunk combine, writes y*sr over k slot ----------------
__global__ __launch_bounds__(256) void wkv_pass3(u16* __restrict__ kvs,
    const float* __restrict__ decay, const float* __restrict__ first,
    const float* __restrict__ chks)
{
    int e = blockIdx.x * 256 + threadIdx.x;
    int idx = e % BC, ci = e / BC;
    int b = idx / Cv, c = idx % Cv;
    float w = decay[c] * (1.f / (float)Tv);
    float u = first[c] * (1.f / (float)Tv);
    const size_t P = (size_t)NCHK * BC;
    size_t so = (size_t)ci * BC + idx;
    size_t base = ((size_t)b * Tv + (size_t)ci * Lc) * KVS + c;
    float sa = chks[3 * P + so], sb2 = chks[4 * P + so], sm = chks[5 * P + so];
    float Ba[SI], Bb[SI], Bm[SI];
#pragma unroll
    for (int si = SI - 1; si >= 0; si--) {
        Ba[si] = sa; Bb[si] = sb2; Bm[si] = sm;
        for (int j = 15; j >= 0; j--) {
            size_t off = base + (size_t)(si * 16 + j) * KVS;
            wkv_step(sa, sb2, sm, w, b2f(kvs[off]), b2f(kvs[off + 768]));
        }
    }
    float fa = chks[0 * P + so], fb2 = chks[1 * P + so], fm = chks[2 * P + so];
#pragma unroll
    for (int si = 0; si < SI; si++) {
        float lk[16], lv[16], la[16], lb[16], lm[16];
        float ta = Ba[si], tb = Bb[si], tm = Bm[si];
#pragma unroll
        for (int j = 15; j >= 0; j--) {
            size_t off = base + (size_t)(si * 16 + j) * KVS;
            lk[j] = b2f(kvs[off]); lv[j] = b2f(kvs[off + 768]);
            la[j] = ta; lb[j] = tb; lm[j] = tm;
            wkv_step(ta, tb, tm, w, lk[j], lv[j]);
        }
#pragma unroll
        for (int j = 0; j < 16; j++) {
            float kk = lk[j] + u;
            float M  = fmaxf(fmaxf(fm, lm[j]), kk);
            float ef = __expf(fm - M);
            float eb = __expf(lm[j] - M);
            float ec = __expf(kk - M);
            float num = ef * fa + eb * la[j] + ec * lv[j];
            float den = ef * fb2 + eb * lb[j] + ec;
            size_t off = base + (size_t)(si * 16 + j) * KVS;
            kvs[off] = f2b(b2f(kvs[off + 1536]) * (num / den));  // y' = sr * y
            wkv_step(fa, fb2, fm, w, lk[j], lv[j]);
        }
    }
}

__global__ __launch_bounds__(256) void fill_signal(float* __restrict__ out, int n, float val)
{
    int i = blockIdx.x * 256 + threadIdx.x;
    if (i < n) out[i] = val;
}

extern "C" void kernel_launch(void* const* d_in, const int* in_sizes, int n_in,
                              void* d_out, int out_size, void* d_ws, size_t ws_size,
                              hipStream_t stream)
{
    const float* x     = (const float*)d_in[0];
    const float* ln1_w = (const float*)d_in[1];
    const float* ln1_b = (const float*)d_in[2];
    const float* ln2_w = (const float*)d_in[3];
    const float* ln2_b = (const float*)d_in[4];
    const float* decay = (const float*)d_in[5];
    const float* first = (const float*)d_in[6];
    const float* Wk_a  = (const float*)d_in[7];
    const float* Wv_a  = (const float*)d_in[8];
    const float* Wr_a  = (const float*)d_in[9];
    const float* Wo_a  = (const float*)d_in[10];
    const float* Wk_f  = (const float*)d_in[11];
    const float* Wv_f  = (const float*)d_in[12];
    const float* Wr_f  = (const float*)d_in[13];
    float* out = (float*)d_out;

    const size_t NCe = (size_t)BT * Cv;        // 12,582,912
    const size_t CC  = (size_t)Cv * Cv;
    const size_t HC  = (size_t)Hv * Cv;
    const size_t SUM = (size_t)6 * NCHK * BC;  // 2,359,296 floats
    const int    MCH = 4096;                   // FFN chunk rows (4 chunks)

    char* p = (char*)d_ws;
    i8*  h8    = (i8*)p;            p += NCe;                 // h_i8 / h2_i8 (reused)
    u16* kvs   = (u16*)p;           p += 3 * NCe * 2;         // k|v|sr bf16 (stride 2304)
    float* x1  = (float*)p;         p += NCe * 4;             // fp32 x after attention
    i8*  wKVR  = (i8*)p;            p += (size_t)KVS * Cv;    // [Wk;Wv;Wr] i8
    i8*  wUG   = (i8*)p;            p += (size_t)(Hv + Cv) * Cv; // [Wk_f;Wr_f] i8
    i8*  wVf8  = (i8*)p;            p += (size_t)Cv * Hv;     // Wv_f i8
    u16* wOa   = (u16*)p;           p += CC * 2;              // Wo bf16
    float* sums = (float*)p;        p += SUM * 4;
    float* chks = (float*)p;        p += SUM * 4;
    float* sAct = (float*)p;        p += (size_t)BT * 4;      // row scales for h / h2
    float* sKf  = (float*)p;        p += (size_t)MCH * 4;     // row scales for kf chunk
    float* sWk  = (float*)p;        p += (size_t)KVS * 4;
    float* sWu  = (float*)p;        p += (size_t)(Hv + Cv) * 4;
    float* sWv  = (float*)p;        p += (size_t)Cv * 4;
    size_t need = (size_t)(p - (char*)d_ws);

    if (ws_size < need) {
        fill_signal<<<(int)((NCe + 255) / 256), 256, 0, stream>>>(out, (int)NCe, (float)(ws_size >> 20));
        return;
    }

    // overlays into dead kvs region (after Wo-GEMM):
    u16* gate  = kvs;                          // BT x 768 bf16
    u16* kf_c  = kvs + NCe;                    // MCH x 3072 bf16 (chunk)
    i8*  kf_8  = (i8*)(kvs + 2 * NCe);         // MCH x 3072 i8 (chunk)

    dim3 blk(256);
    // weight quantization (merged launches) + Wo bf16
    quant_w3<<<KVS, blk, 0, stream>>>(Wk_a, Wv_a, Wr_a, Cv, Cv, wKVR, sWk, Cv);
    quant_w3<<<Hv + Cv, blk, 0, stream>>>(Wk_f, Wr_f, nullptr, Hv, Cv, wUG, sWu, Cv);
    quant_w3<<<Cv, blk, 0, stream>>>(Wv_f, nullptr, nullptr, Cv, 0, wVf8, sWv, Hv);
    cvt_f2b<<<(int)(CC / 4 + 255) / 256, blk, 0, stream>>>(Wo_a, wOa, (int)(CC / 4));

    // 1. h = LN1(x) -> i8 + row scales
    ln_q8<<<BT, blk, 0, stream>>>(x, ln1_w, ln1_b, h8, sAct);
    // 2. fused [k|v|sr] = h @ [Wk;Wv;Wr]^T (i8), sigmoid cols >= 1536. grid 2304
    gemm128q<0><<<dim3((BT / 128) * (KVS / 128)), blk, 0, stream>>>(
        h8, wKVR, kvs, nullptr, Cv, Cv, Cv, KVS, 0, KVS / 128, 1536,
        sAct, sWk, nullptr, nullptr);
    // 3. bidirectional WKV; y*sr written over k slot
    wkv_pass1<<<(2 * BC * NCHK) / 256, blk, 0, stream>>>(kvs, decay, sums);
    wkv_pass2<<<(2 * BC) / 256, blk, 0, stream>>>(decay, sums, chks);
    wkv_pass3<<<(BC * NCHK) / 256, blk, 0, stream>>>(kvs, decay, first, chks);
    // 4. x1 = x + (sr*y) @ Wo^T (bf16). grid 768
    gemm128<4><<<dim3((BT / 128) * (Cv / 128)), blk, 0, stream>>>(
        kvs, wOa, x1, Cv, KVS, Cv, Cv, Cv / 128, x);
    // 5. h2 = LN2(x1) -> i8 + row scales
    ln_q8<<<BT, blk, 0, stream>>>(x1, ln2_w, ln2_b, h8, sAct);
    // 6. FFN in 4 chunks of 4096 rows: fused up+gate (i8) -> quant kf -> down (i8)
    for (int j = 0; j < 4; j++) {
        size_t ro = (size_t)j * MCH;
        gemm128q<5><<<dim3((MCH / 128) * ((Hv + Cv) / 128)), blk, 0, stream>>>(
            h8 + ro * Cv, wUG, kf_c, gate + ro * Cv, Cv, Cv, Cv, Hv, Cv,
            (Hv + Cv) / 128, Hv, sAct + ro, sWu, nullptr, nullptr);
        quant_bf<<<MCH, blk, 0, stream>>>(kf_c, kf_8, sKf, Hv);
        gemm128q<3><<<dim3((MCH / 128) * (Cv / 128)), blk, 0, stream>>>(
            kf_8, wVf8, out + ro * Cv, nullptr, Hv, Hv, Hv, Cv, 0, Cv / 128, 0,
            sKf, sWv, x1 + ro * Cv, gate + ro * Cv);
    }
}

// Round 10
// 469.399 us; speedup vs baseline: 1.1541x; 1.0365x over previous
//
#include <hip/hip_runtime.h>
#include <math.h>

typedef unsigned short u16;
typedef signed char i8;
typedef short s8v __attribute__((ext_vector_type(8)));   // 8 bf16
typedef float f4v __attribute__((ext_vector_type(4)));
typedef int   i4v __attribute__((ext_vector_type(4)));   // 16 i8 / 4 i32 acc

constexpr int Bv = 8, Tv = 2048, Cv = 768, Hv = 3072;
constexpr int BT = Bv * Tv;       // 16384 tokens
constexpr int BC = Bv * Cv;       // 6144 channels
constexpr int Lc = 32;            // WKV chunk length
constexpr int NCHK = Tv / Lc;     // 64 chunks
constexpr int SI = Lc / 16;       // 2 sub-chunks
constexpr int KVS = 2304;         // fused k|v|sr row stride

__device__ __forceinline__ float b2f(u16 x) { return __uint_as_float(((unsigned)x) << 16); }
__device__ __forceinline__ u16 f2b(float f) {
    unsigned u = __float_as_uint(f);
    return (u16)((u + 0x7fffu + ((u >> 16) & 1u)) >> 16);   // RNE
}

#define GLOAD_LDS(g, l) __builtin_amdgcn_global_load_lds( \
    (const __attribute__((address_space(1))) void*)(g),    \
    (__attribute__((address_space(3))) void*)(l), 16, 0, 0)
#define BAR()  __builtin_amdgcn_s_barrier()
#define VM4()  asm volatile("s_waitcnt vmcnt(4)" ::: "memory")
#define VM0()  asm volatile("s_waitcnt vmcnt(0)" ::: "memory")

// ---------------- LayerNorm fp32 -> per-row int8 + scale ----------------
__global__ __launch_bounds__(256) void ln_q8(const float* __restrict__ x,
    const float* __restrict__ w, const float* __restrict__ b,
    i8* __restrict__ outq, float* __restrict__ sA)
{
    __shared__ float sh[8];
    int row = blockIdx.x;
    const float* xr = x + (size_t)row * Cv;
    float vals[3];
    float s = 0.f, s2 = 0.f;
#pragma unroll
    for (int i = 0; i < 3; i++) {
        float t = xr[threadIdx.x + 256 * i];
        vals[i] = t; s += t; s2 += t * t;
    }
#pragma unroll
    for (int off = 32; off > 0; off >>= 1) {
        s  += __shfl_down(s, off);
        s2 += __shfl_down(s2, off);
    }
    int wid = threadIdx.x >> 6;
    if ((threadIdx.x & 63) == 0) { sh[wid] = s; sh[4 + wid] = s2; }
    __syncthreads();
    if (threadIdx.x == 0) {
        sh[0] = sh[0] + sh[1] + sh[2] + sh[3];
        sh[4] = sh[4] + sh[5] + sh[6] + sh[7];
    }
    __syncthreads();
    float mean = sh[0] * (1.f / Cv);
    float var  = sh[4] * (1.f / Cv) - mean * mean;
    float rstd = rsqrtf(var + 1e-5f);
    float nv[3], am = 0.f;
#pragma unroll
    for (int i = 0; i < 3; i++) {
        int j = threadIdx.x + 256 * i;
        nv[i] = (vals[i] - mean) * rstd * w[j] + b[j];
        am = fmaxf(am, fabsf(nv[i]));
    }
#pragma unroll
    for (int off = 32; off > 0; off >>= 1) am = fmaxf(am, __shfl_xor(am, off));
    __syncthreads();
    if ((threadIdx.x & 63) == 0) sh[wid] = am;
    __syncthreads();
    am = fmaxf(fmaxf(sh[0], sh[1]), fmaxf(sh[2], sh[3]));
    am = fmaxf(am, 1e-20f);
    float inv = 127.f / am;
    if (threadIdx.x == 0) sA[row] = am * (1.f / 127.f);
    i8* orow = outq + (size_t)row * Cv;
#pragma unroll
    for (int i = 0; i < 3; i++)
        orow[threadIdx.x + 256 * i] = (i8)(int)rintf(nv[i] * inv);
}

// ---------------- all six K=768 weights -> one stacked i8 buffer ----------------
// rows: [0,768) Wk_a | [768,1536) Wv_a | [1536,2304) Wr_a | [2304,3072) Wo_a
//       [3072,6144) Wk_f | [6144,6912) Wr_f
__global__ __launch_bounds__(256) void quant_w6(const float* __restrict__ wk,
    const float* __restrict__ wv, const float* __restrict__ wr,
    const float* __restrict__ wo, const float* __restrict__ wkf,
    const float* __restrict__ wrf, i8* __restrict__ dst, float* __restrict__ sW)
{
    __shared__ float sh[4];
    int row = blockIdx.x;
    const float* src;
    if      (row < 768)  src = wk  + (size_t)row * Cv;
    else if (row < 1536) src = wv  + (size_t)(row - 768) * Cv;
    else if (row < 2304) src = wr  + (size_t)(row - 1536) * Cv;
    else if (row < 3072) src = wo  + (size_t)(row - 2304) * Cv;
    else if (row < 6144) src = wkf + (size_t)(row - 3072) * Cv;
    else                 src = wrf + (size_t)(row - 6144) * Cv;
    i8* dr = dst + (size_t)row * Cv;
    float am = 0.f;
    for (int j = threadIdx.x; j < Cv; j += 256) am = fmaxf(am, fabsf(src[j]));
#pragma unroll
    for (int off = 32; off > 0; off >>= 1) am = fmaxf(am, __shfl_xor(am, off));
    int wid = threadIdx.x >> 6;
    if ((threadIdx.x & 63) == 0) sh[wid] = am;
    __syncthreads();
    am = fmaxf(fmaxf(sh[0], sh[1]), fmaxf(sh[2], sh[3]));
    am = fmaxf(am, 1e-20f);
    float inv = 127.f / am;
    if (threadIdx.x == 0) sW[row] = am * (1.f / 127.f);
    for (int j = threadIdx.x; j < Cv; j += 256) dr[j] = (i8)(int)rintf(src[j] * inv);
}

// ---------------- single fp32 weight (K=3072) -> i8 ----------------
__global__ __launch_bounds__(256) void quant_w1(const float* __restrict__ src0,
    i8* __restrict__ dst, float* __restrict__ sW, int K)
{
    __shared__ float sh[4];
    int row = blockIdx.x;
    const float* src = src0 + (size_t)row * K;
    i8* dr = dst + (size_t)row * K;
    float am = 0.f;
    for (int j = threadIdx.x; j < K; j += 256) am = fmaxf(am, fabsf(src[j]));
#pragma unroll
    for (int off = 32; off > 0; off >>= 1) am = fmaxf(am, __shfl_xor(am, off));
    int wid = threadIdx.x >> 6;
    if ((threadIdx.x & 63) == 0) sh[wid] = am;
    __syncthreads();
    am = fmaxf(fmaxf(sh[0], sh[1]), fmaxf(sh[2], sh[3]));
    am = fmaxf(am, 1e-20f);
    float inv = 127.f / am;
    if (threadIdx.x == 0) sW[row] = am * (1.f / 127.f);
    for (int j = threadIdx.x; j < K; j += 256) dr[j] = (i8)(int)rintf(src[j] * inv);
}

// ---------------- per-row bf16 -> i8 (kf), vectorized ----------------
__global__ __launch_bounds__(256) void quant_bf(const u16* __restrict__ src,
    i8* __restrict__ dst, float* __restrict__ sA, int K)
{
    __shared__ float sh[4];
    int row = blockIdx.x;
    const u16* sr_ = src + (size_t)row * K;
    i8* dr = dst + (size_t)row * K;
    float am = 0.f;
    for (int j = threadIdx.x * 8; j < K; j += 2048) {
        s8v v = *(const s8v*)(sr_ + j);
#pragma unroll
        for (int b = 0; b < 8; b++) am = fmaxf(am, fabsf(b2f((u16)v[b])));
    }
#pragma unroll
    for (int off = 32; off > 0; off >>= 1) am = fmaxf(am, __shfl_xor(am, off));
    int wid = threadIdx.x >> 6;
    if ((threadIdx.x & 63) == 0) sh[wid] = am;
    __syncthreads();
    am = fmaxf(fmaxf(sh[0], sh[1]), fmaxf(sh[2], sh[3]));
    am = fmaxf(am, 1e-20f);
    float inv = 127.f / am;
    if (threadIdx.x == 0) sA[row] = am * (1.f / 127.f);
    for (int j = threadIdx.x * 8; j < K; j += 2048) {
        s8v v = *(const s8v*)(sr_ + j);
        unsigned lo = 0, hi = 0;
#pragma unroll
        for (int b = 0; b < 4; b++) {
            lo |= ((unsigned)(unsigned char)(i8)(int)rintf(b2f((u16)v[b]) * inv)) << (8 * b);
            hi |= ((unsigned)(unsigned char)(i8)(int)rintf(b2f((u16)v[4 + b]) * inv)) << (8 * b);
        }
        uint2 o2; o2.x = lo; o2.y = hi;
        *(uint2*)(dr + j) = o2;
    }
}

// ---------------- y' (bf16, stride KVS) -> per-row i8 + scale ----------------
__global__ __launch_bounds__(256) void quant_y(const u16* __restrict__ kvs,
    i8* __restrict__ y8, float* __restrict__ sY)
{
    __shared__ float sh[4];
    int row = blockIdx.x;
    const u16* yr = kvs + (size_t)row * KVS;
    float v[3], am = 0.f;
#pragma unroll
    for (int i = 0; i < 3; i++) {
        v[i] = b2f(yr[threadIdx.x + 256 * i]);
        am = fmaxf(am, fabsf(v[i]));
    }
#pragma unroll
    for (int off = 32; off > 0; off >>= 1) am = fmaxf(am, __shfl_xor(am, off));
    int wid = threadIdx.x >> 6;
    if ((threadIdx.x & 63) == 0) sh[wid] = am;
    __syncthreads();
    am = fmaxf(fmaxf(sh[0], sh[1]), fmaxf(sh[2], sh[3]));
    am = fmaxf(am, 1e-20f);
    float inv = 127.f / am;
    if (threadIdx.x == 0) sY[row] = am * (1.f / 127.f);
    i8* orow = y8 + (size_t)row * Cv;
#pragma unroll
    for (int i = 0; i < 3; i++)
        orow[threadIdx.x + 256 * i] = (i8)(int)rintf(v[i] * inv);
}

// ---------------- int8 MFMA GEMM, 3-buffer / 1-barrier-per-phase, 3 blocks/CU -------
// BM=BN=128, BK=64, 256 thr = 4 waves (2x2); per-wave C = 64x64 (4x4 frags),
// mfma_i32_16x16x64_i8 (one instr = full BK). LDS: 3 bufs x {A,B} x [128 x 64 i8]
// = 48 KiB -> 3 blocks/CU. Per phase: 8 ds_read | stage tile t+2 (4 gload_lds)
// | 16 MFMA | vmcnt(4) gate (waits tile t+1, issued a full phase earlier) | BAR.
// One barrier/phase is safe with 3 bufs: the staged buf (t+2)%3 equals the buf read
// at t-1, and those reads complete before the t-1 barrier (MFMA's lgkm wait).
// 16B-slot swizzle slot^=(row>>1)&3 (pre-swizzled source + swizzled ds_read).
// Grid 1-D nb=(M/128)*ny, nb%8==0, XCD-chunk + y-fast decode. K%128==0 (NKT>=2).
// EPI 0: bf16 out, sigmoid col>=sigoff | 3: f32 e0+b2f(e1)*r | 4: f32 e0+r | 5: dual
template<int EPI>
__global__ __launch_bounds__(256, 3) void gemm128q(const i8* __restrict__ A,
    const i8* __restrict__ W, void* __restrict__ outv, void* __restrict__ out2,
    int K, int lda, int ldw, int ldc, int ldc2, int ny, int sigoff,
    const float* __restrict__ sA, const float* __restrict__ sW,
    const float* __restrict__ e0, const u16* __restrict__ e1)
{
    __shared__ i8 lds[3][2][8192];             // [buf][A/B][128*64]
    const int tid = threadIdx.x;
    const int wv = tid >> 6, l = tid & 63;
    const int nb = (int)gridDim.x, bid = (int)blockIdx.x;
    const int q = nb >> 3;
    const int sw = (bid & 7) * q + (bid >> 3);
    const int bm = (sw / ny) * 128, bn = (sw % ny) * 128;
    const int wr = wv >> 1, wc = wv & 1;
    const int row0 = wv * 32 + (l >> 2);
    const int scol = ((l & 3) ^ ((l >> 3) & 3)) << 4;        // i8 units
    const i8* srcA = A + (size_t)(bm + row0) * lda + scol;
    const i8* srcB = W + (size_t)(bn + row0) * ldw + scol;
#define STG(buf, kt) { \
    const size_t kc = (size_t)(kt) * 64; \
    GLOAD_LDS(srcA + kc,                    &lds[buf][0][wv * 2048]); \
    GLOAD_LDS(srcA + kc + (size_t)16 * lda, &lds[buf][0][wv * 2048 + 1024]); \
    GLOAD_LDS(srcB + kc,                    &lds[buf][1][wv * 2048]); \
    GLOAD_LDS(srcB + kc + (size_t)16 * ldw, &lds[buf][1][wv * 2048 + 1024]); }
    const int swz = ((l >> 4) ^ ((l >> 1) & 3)) << 4;
    const int ab  = (wr * 64 + (l & 15)) * 64 + swz;
    const int bb  = (wc * 64 + (l & 15)) * 64 + swz;
#define RD(pbuf) { \
    _Pragma("unroll") \
    for (int i = 0; i < 4; i++) { \
        a4[i] = *(const i4v*)&lds[pbuf][0][ab + i * 1024]; \
        b4[i] = *(const i4v*)&lds[pbuf][1][bb + i * 1024]; } }
#define MF() { \
    __builtin_amdgcn_s_setprio(1); \
    _Pragma("unroll") \
    for (int mm = 0; mm < 4; mm++) \
        _Pragma("unroll") \
        for (int nn = 0; nn < 4; nn++) \
            acc[mm][nn] = __builtin_amdgcn_mfma_i32_16x16x64_i8( \
                a4[mm], b4[nn], acc[mm][nn], 0, 0, 0); \
    __builtin_amdgcn_s_setprio(0); }

    i4v acc[4][4] = {};
    const int NKT = K >> 6;
    STG(0, 0); STG(1, 1);
    VM4();                                     // tile 0 landed
    BAR();
    int cur = 0;
    for (int t = 0; t < NKT; ++t) {
        i4v a4[4], b4[4];
        RD(cur);
        const int n2 = cur >= 1 ? cur - 1 : 2;             // (cur+2)%3
        if (t + 2 < NKT) STG(n2, t + 2);
        MF();
        if (t + 2 < NKT)      VM4();           // tile t+1 (issued 1 phase ago) landed
        else if (t + 1 < NKT) VM0();           // drain last prefetch
        BAR();
        cur = cur >= 2 ? 0 : cur + 1;
    }
#undef STG
#undef RD
#undef MF
    // epilogue: C row=(lane>>4)*4+i, col=lane&15 per 16x16 fragment
    const int r0 = bm + wr * 64 + ((l >> 4) << 2);
    const int c0 = bn + wc * 64 + (l & 15);
    float sw4[4];
#pragma unroll
    for (int nf = 0; nf < 4; nf++) sw4[nf] = sW[c0 + nf * 16];
#pragma unroll
    for (int mf = 0; mf < 4; mf++)
#pragma unroll
        for (int i = 0; i < 4; i++) {
            const int row = r0 + mf * 16 + i;
            const float sar = sA[row];
#pragma unroll
            for (int nf = 0; nf < 4; nf++) {
                const int col = c0 + nf * 16;
                float r = (float)acc[mf][nf][i] * sar * sw4[nf];
                if (EPI == 0) {
                    if (col >= sigoff) r = 1.f / (1.f + __expf(-r));
                    ((u16*)outv)[(size_t)row * ldc + col] = f2b(r);
                } else if (EPI == 3) {
                    size_t o = (size_t)row * ldc + col;
                    ((float*)outv)[o] = fmaf(b2f(e1[o]), r, e0[o]);
                } else if (EPI == 4) {
                    size_t o = (size_t)row * ldc + col;
                    ((float*)outv)[o] = e0[o] + r;
                } else if (EPI == 5) {
                    if (col < sigoff) {
                        float t2 = fmaxf(r, 0.f);
                        ((u16*)outv)[(size_t)row * ldc + col] = f2b(t2 * t2);
                    } else {
                        float sg = 1.f / (1.f + __expf(-r));
                        ((u16*)out2)[(size_t)row * ldc2 + (col - sigoff)] = f2b(sg);
                    }
                }
            }
        }
}

// ---------------- WKV helpers ----------------
__device__ __forceinline__ void wkv_step(float& a, float& b, float& m,
                                         float w, float kt, float vt)
{
    float mm = fmaxf(m + w, kt);
    float e1 = __expf(m + w - mm);
    float e2 = __expf(kt - mm);
    a = e1 * a + e2 * vt;
    b = e1 * b + e2;
    m = mm;
}
__device__ __forceinline__ void wkv_merge(float& a, float& b, float& m,
                                          float shift, float a2, float b2, float m2)
{
    float ms = m + shift;
    float mm = fmaxf(ms, m2);
    float e1 = __expf(ms - mm);
    float e2 = __expf(m2 - mm);
    a = e1 * a + e2 * a2;
    b = e1 * b + e2 * b2;
    m = mm;
}

// ---------------- WKV pass 1: per-chunk summaries, direction-split ----------------
__global__ __launch_bounds__(256) void wkv_pass1(const u16* __restrict__ kvs,
    const float* __restrict__ decay, float* __restrict__ sums)
{
    int e = blockIdx.x * 256 + threadIdx.x;
    const int PN = NCHK * BC;
    int dir = e / PN, r = e % PN;
    int idx = r % BC, ci = r / BC;
    int b = idx / Cv, c = idx % Cv;
    float w = decay[c] * (1.f / (float)Tv);
    size_t base = ((size_t)b * Tv + (size_t)ci * Lc) * KVS + c;
    const size_t P = (size_t)NCHK * BC;
    size_t so = (size_t)ci * BC + idx;
    float a = 0.f, bb = 0.f, m = -1e38f;
    if (dir == 0) {
        for (int t = 0; t < Lc; t++) {
            size_t off = base + (size_t)t * KVS;
            wkv_step(a, bb, m, w, b2f(kvs[off]), b2f(kvs[off + 768]));
        }
        sums[0 * P + so] = a; sums[1 * P + so] = bb; sums[2 * P + so] = m;
    } else {
        for (int t = Lc - 1; t >= 0; t--) {
            size_t off = base + (size_t)t * KVS;
            wkv_step(a, bb, m, w, b2f(kvs[off]), b2f(kvs[off + 768]));
        }
        sums[3 * P + so] = a; sums[4 * P + so] = bb; sums[5 * P + so] = m;
    }
}

// ---------------- WKV pass 2: scan chunk summaries, direction-split ----------------
__global__ __launch_bounds__(256) void wkv_pass2(const float* __restrict__ decay,
    const float* __restrict__ sums, float* __restrict__ chks)
{
    int e = blockIdx.x * 256 + threadIdx.x;
    int dir = e / BC, idx = e % BC;
    int c = idx % Cv;
    float shift = decay[c] * (1.f / (float)Tv) * (float)Lc;
    const size_t P = (size_t)NCHK * BC;
    float a = 0.f, bb = 0.f, m = -1e38f;
    if (dir == 0) {
        for (int ci = 0; ci < NCHK; ci++) {
            size_t so = (size_t)ci * BC + idx;
            chks[0 * P + so] = a; chks[1 * P + so] = bb; chks[2 * P + so] = m;
            wkv_merge(a, bb, m, shift, sums[0 * P + so], sums[1 * P + so], sums[2 * P + so]);
        }
    } else {
        for (int ci = NCHK - 1; ci >= 0; ci--) {
            size_t so = (size_t)ci * BC + idx;
            chks[3 * P + so] = a; chks[4 * P + so] = bb; chks[5 * P + so] = m;
            wkv_merge(a, bb, m, shift, sums[3 * P + so], sums[4 * P + so], sums[5 * P + so]);
        }
    }
}

// ---------------- WKV pass 3: per-chunk combine, writes y*sr over k slot ----------------
__global__ __launch_bounds__(256) void wkv_pass3(u16* __restrict__ kvs,
    const float* __restrict__ decay, const float* __restrict__ first,
    const float* __restrict__ chks)
{
    int e = blockIdx.x * 256 + threadIdx.x;
    int idx = e % BC, ci = e / BC;
    int b = idx / Cv, c = idx % Cv;
    float w = decay[c] * (1.f / (float)Tv);
    float u = first[c] * (1.f / (float)Tv);
    const size_t P = (size_t)NCHK * BC;
    size_t so = (size_t)ci * BC + idx;
    size_t base = ((size_t)b * Tv + (size_t)ci * Lc) * KVS + c;
    float sa = chks[3 * P + so], sb2 = chks[4 * P + so], sm = chks[5 * P + so];
    float Ba[SI], Bb[SI], Bm[SI];
#pragma unroll
    for (int si = SI - 1; si >= 0; si--) {
        Ba[si] = sa; Bb[si] = sb2; Bm[si] = sm;
        for (int j = 15; j >= 0; j--) {
            size_t off = base + (size_t)(si * 16 + j) * KVS;
            wkv_step(sa, sb2, sm, w, b2f(kvs[off]), b2f(kvs[off + 768]));
        }
    }
    float fa = chks[0 * P + so], fb2 = chks[1 * P + so], fm = chks[2 * P + so];
#pragma unroll
    for (int si = 0; si < SI; si++) {
        float lk[16], lv[16], la[16], lb[16], lm[16];
        float ta = Ba[si], tb = Bb[si], tm = Bm[si];
#pragma unroll
        for (int j = 15; j >= 0; j--) {
            size_t off = base + (size_t)(si * 16 + j) * KVS;
            lk[j] = b2f(kvs[off]); lv[j] = b2f(kvs[off + 768]);
            la[j] = ta; lb[j] = tb; lm[j] = tm;
            wkv_step(ta, tb, tm, w, lk[j], lv[j]);
        }
#pragma unroll
        for (int j = 0; j < 16; j++) {
            float kk = lk[j] + u;
            float M  = fmaxf(fmaxf(fm, lm[j]), kk);
            float ef = __expf(fm - M);
            float eb = __expf(lm[j] - M);
            float ec = __expf(kk - M);
            float num = ef * fa + eb * la[j] + ec * lv[j];
            float den = ef * fb2 + eb * lb[j] + ec;
            size_t off = base + (size_t)(si * 16 + j) * KVS;
            kvs[off] = f2b(b2f(kvs[off + 1536]) * (num / den));  // y' = sr * y
            wkv_step(fa, fb2, fm, w, lk[j], lv[j]);
        }
    }
}

__global__ __launch_bounds__(256) void fill_signal(float* __restrict__ out, int n, float val)
{
    int i = blockIdx.x * 256 + threadIdx.x;
    if (i < n) out[i] = val;
}

extern "C" void kernel_launch(void* const* d_in, const int* in_sizes, int n_in,
                              void* d_out, int out_size, void* d_ws, size_t ws_size,
                              hipStream_t stream)
{
    const float* x     = (const float*)d_in[0];
    const float* ln1_w = (const float*)d_in[1];
    const float* ln1_b = (const float*)d_in[2];
    const float* ln2_w = (const float*)d_in[3];
    const float* ln2_b = (const float*)d_in[4];
    const float* decay = (const float*)d_in[5];
    const float* first = (const float*)d_in[6];
    const float* Wk_a  = (const float*)d_in[7];
    const float* Wv_a  = (const float*)d_in[8];
    const float* Wr_a  = (const float*)d_in[9];
    const float* Wo_a  = (const float*)d_in[10];
    const float* Wk_f  = (const float*)d_in[11];
    const float* Wv_f  = (const float*)d_in[12];
    const float* Wr_f  = (const float*)d_in[13];
    float* out = (float*)d_out;

    const size_t NCe = (size_t)BT * Cv;        // 12,582,912
    const size_t HC  = (size_t)Hv * Cv;
    const size_t SUM = (size_t)6 * NCHK * BC;
    const int    MCH = 4096;                   // FFN chunk rows (4 chunks)
    const int    WR  = 6912;                   // stacked K=768 weight rows

    char* p = (char*)d_ws;
    i8*  h8    = (i8*)p;            p += NCe;                 // h1 / y8 / h2 (serial reuse)
    u16* kvs   = (u16*)p;           p += 3 * NCe * 2;         // k|v|sr bf16 (stride 2304)
    float* x1  = (float*)p;         p += NCe * 4;             // fp32 x after attention
    i8*  wAll  = (i8*)p;            p += (size_t)WR * Cv;     // stacked K=768 weights i8
    i8*  wVf8  = (i8*)p;            p += (size_t)Cv * Hv;     // Wv_f i8
    float* sums = (float*)p;        p += SUM * 4;
    float* chks = (float*)p;        p += SUM * 4;
    float* sAct = (float*)p;        p += (size_t)BT * 4;      // h / h2 row scales
    float* sY   = (float*)p;        p += (size_t)BT * 4;      // y' row scales
    float* sKf  = (float*)p;        p += (size_t)MCH * 4;     // kf chunk row scales
    float* sWall = (float*)p;       p += (size_t)WR * 4;
    float* sWv  = (float*)p;        p += (size_t)Cv * 4;
    size_t need = (size_t)(p - (char*)d_ws);

    if (ws_size < need) {
        fill_signal<<<(int)((NCe + 255) / 256), 256, 0, stream>>>(out, (int)NCe, (float)(ws_size >> 20));
        return;
    }

    // overlays into dead kvs region (after quant_y + Wo-GEMM):
    u16* gate  = kvs;                          // BT x 768 bf16
    u16* kf_c  = kvs + NCe;                    // MCH x 3072 bf16 (chunk)
    i8*  kf_8  = (i8*)(kvs + 2 * NCe);         // MCH x 3072 i8 (chunk)

    dim3 blk(256);
    // weight quantization: one stacked K=768 dispatch + Wv_f
    quant_w6<<<WR, blk, 0, stream>>>(Wk_a, Wv_a, Wr_a, Wo_a, Wk_f, Wr_f, wAll, sWall);
    quant_w1<<<Cv, blk, 0, stream>>>(Wv_f, wVf8, sWv, Hv);

    // 1. h = LN1(x) -> i8 + row scales
    ln_q8<<<BT, blk, 0, stream>>>(x, ln1_w, ln1_b, h8, sAct);
    // 2. fused [k|v|sr] = h @ [Wk;Wv;Wr]^T (i8), sigmoid cols >= 1536. grid 2304
    gemm128q<0><<<dim3((BT / 128) * (KVS / 128)), blk, 0, stream>>>(
        h8, wAll, kvs, nullptr, Cv, Cv, Cv, KVS, 0, KVS / 128, 1536,
        sAct, sWall, nullptr, nullptr);
    // 3. bidirectional WKV; y' = sr*y written over k slot
    wkv_pass1<<<(2 * BC * NCHK) / 256, blk, 0, stream>>>(kvs, decay, sums);
    wkv_pass2<<<(2 * BC) / 256, blk, 0, stream>>>(decay, sums, chks);
    wkv_pass3<<<(BC * NCHK) / 256, blk, 0, stream>>>(kvs, decay, first, chks);
    // 4. y' -> i8 (h1 dead, reuse h8); x1 = x + y8 @ Wo^T. grid 768
    quant_y<<<BT, blk, 0, stream>>>(kvs, h8, sY);
    gemm128q<4><<<dim3((BT / 128) * (Cv / 128)), blk, 0, stream>>>(
        h8, wAll + (size_t)2304 * Cv, x1, nullptr, Cv, Cv, Cv, Cv, 0, Cv / 128, 0,
        sY, sWall + 2304, x, nullptr);
    // 5. h2 = LN2(x1) -> i8 + row scales
    ln_q8<<<BT, blk, 0, stream>>>(x1, ln2_w, ln2_b, h8, sAct);
    // 6. FFN in 4 chunks: fused up+gate (i8) -> quant kf -> down (i8)
    for (int j = 0; j < 4; j++) {
        size_t ro = (size_t)j * MCH;
        gemm128q<5><<<dim3((MCH / 128) * ((Hv + Cv) / 128)), blk, 0, stream>>>(
            h8 + ro * Cv, wAll + (size_t)3072 * Cv, kf_c, gate + ro * Cv,
            Cv, Cv, Cv, Hv, Cv, (Hv + Cv) / 128, Hv, sAct + ro, sWall + 3072,
            nullptr, nullptr);
        quant_bf<<<MCH, blk, 0, stream>>>(kf_c, kf_8, sKf, Hv);
        gemm128q<3><<<dim3((MCH / 128) * (Cv / 128)), blk, 0, stream>>>(
            kf_8, wVf8, out + ro * Cv, nullptr, Hv, Hv, Hv, Cv, 0, Cv / 128, 0,
            sKf, sWv, x1 + ro * Cv, gate + ro * Cv);
    }
}